// Round 10
// baseline (308.802 us; speedup 1.0000x reference)
//
#include <hip/hip_runtime.h>
#include <hip/hip_bf16.h>
#include <math.h>

typedef __attribute__((ext_vector_type(8))) short short8;
typedef __attribute__((ext_vector_type(4))) float f32x4;

__device__ inline unsigned short f2bf(float f) {
    unsigned int u = __float_as_uint(f);
    unsigned int r = u + 0x7fffu + ((u >> 16) & 1u);   // RTNE
    return (unsigned short)(r >> 16);
}
__device__ inline float bf2f(unsigned short h) {
    return __uint_as_float(((unsigned int)h) << 16);
}

// ---------------- fused prep: convX (bf16) + convW1 (bf16,T) + convW2 (bf16,T) + degree count ----------------

__global__ void prep_kernel(const float* __restrict__ x,
                            unsigned short* __restrict__ Xh,
                            const float* __restrict__ W1, unsigned short* __restrict__ W1hT,
                            const float* __restrict__ W2, unsigned short* __restrict__ W2hT,
                            const int* __restrict__ dst, int* __restrict__ deg,
                            int M, int K1, int Kp1, int H, int E,
                            int bX, int bW1, int bW2)
{
    const int b = blockIdx.x;
    const int tid = threadIdx.x;
    if (b < bX) {
        int id = b * 256 + tid;
        if (id < M * Kp1) {
            int r = id / Kp1;
            int k = id - r * Kp1;
            float v = (k < K1) ? x[(size_t)r * K1 + k] : 0.f;
            Xh[id] = f2bf(v);
        }
    } else if (b < bX + bW1) {
        int id = (b - bX) * 256 + tid;
        if (id < H * Kp1) {
            int nrow = id / Kp1;
            int k = id - nrow * Kp1;
            float v = (k < K1) ? W1[(size_t)k * H + nrow] : 0.f;
            W1hT[id] = f2bf(v);
        }
    } else if (b < bX + bW1 + bW2) {
        int id = (b - bX - bW1) * 256 + tid;
        if (id < H * H) {
            int nrow = id / H;
            int k = id - nrow * H;
            W2hT[id] = f2bf(W2[(size_t)k * H + nrow]);
        }
    } else {
        int e = (b - bX - bW1 - bW2) * 256 + tid;
        if (e < E) atomicAdd(&deg[dst[e]], 1);
    }
}

// ---------------- one-block scan (1024 threads) -> row_start + cursor; also dinv ----------------

__global__ __launch_bounds__(1024) void scan_kernel(const int* __restrict__ deg,
                                                    int* __restrict__ row_start,
                                                    int* __restrict__ cursor,
                                                    float* __restrict__ dinv, int n)
{
    __shared__ int swave[16];
    __shared__ int s_run;
    const int lane = threadIdx.x & 63;
    const int w = threadIdx.x >> 6;
    if (threadIdx.x == 0) s_run = 0;
    __syncthreads();

    for (int base = 0; base < n; base += 1024) {
        int i = base + threadIdx.x;
        int v = (i < n) ? deg[i] : 0;
        int incl = v;
#pragma unroll
        for (int off = 1; off < 64; off <<= 1) {
            int t = __shfl_up(incl, off);
            if (lane >= off) incl += t;
        }
        if (lane == 63) swave[w] = incl;
        __syncthreads();
        int wpre = 0, total = 0;
#pragma unroll
        for (int j = 0; j < 16; j++) {
            int sv = swave[j];
            if (j < w) wpre += sv;
            total += sv;
        }
        int run = s_run;
        if (i < n) {
            int rs = run + wpre + incl - v;
            row_start[i] = rs;
            cursor[i] = rs;
            dinv[i] = rsqrtf((float)v + 1.0f);
        }
        __syncthreads();
        if (threadIdx.x == 0) s_run = run + total;
        __syncthreads();
    }
    if (threadIdx.x == 0) row_start[n] = s_run;
}

// ---------------- CSR fill (absolute cursor) ----------------

__global__ void fill_csr_kernel(const int* __restrict__ src, const int* __restrict__ dst,
                                int* __restrict__ cursor, int* __restrict__ csr_src, int E)
{
    int e = blockIdx.x * blockDim.x + threadIdx.x;
    if (e >= E) return;
    int d = dst[e];
    int pos = atomicAdd(&cursor[d], 1);
    csr_src[pos] = src[e];
}

// ---------------- LDS-free barrier-free bf16 MFMA GEMM: C[M,N](bf16) = A @ B ----------------
// A [M][Kp] bf16 row-major; BT [N][Kp] bf16 (B transposed). Tile 64x64, 256 threads (4 waves),
// wave w owns rows w*16..w*16+15 x all 64 cols: 4 MFMAs + 5 direct-global fragment loads / K=32.
// 1256 blocks -> ~20 waves/CU; latencies hidden by TLP, no __syncthreads anywhere.
// XCD swizzle: blocks with equal j%8 share the A row-strip on one XCD's L2.

__global__ __launch_bounds__(256) void gemm_bf16_kernel(
    const unsigned short* __restrict__ A, const unsigned short* __restrict__ BT,
    unsigned short* __restrict__ C, int M, int N, int Kp, int tiles_m)
{
    const int j = blockIdx.x;
    const int tn = (j >> 3) & 7;
    const int tm = (j >> 6) * 8 + (j & 7);
    if (tm >= tiles_m) return;

    const int wave = threadIdx.x >> 6;
    const int lane = threadIdx.x & 63;
    const int quad = lane >> 4;
    const int l16  = lane & 15;

    int arow = tm * 64 + wave * 16 + l16;
    if (arow >= M) arow = M - 1;                 // clamp; stores are guarded
    const unsigned short* pA = A + (size_t)arow * Kp + quad * 8;

    const unsigned short* pB0 = BT + (size_t)(tn * 64 +  0 + l16) * Kp + quad * 8;
    const unsigned short* pB1 = BT + (size_t)(tn * 64 + 16 + l16) * Kp + quad * 8;
    const unsigned short* pB2 = BT + (size_t)(tn * 64 + 32 + l16) * Kp + quad * 8;
    const unsigned short* pB3 = BT + (size_t)(tn * 64 + 48 + l16) * Kp + quad * 8;

    f32x4 acc0 = {0.f,0.f,0.f,0.f}, acc1 = {0.f,0.f,0.f,0.f};
    f32x4 acc2 = {0.f,0.f,0.f,0.f}, acc3 = {0.f,0.f,0.f,0.f};

#pragma unroll 4
    for (int k0 = 0; k0 < Kp; k0 += 32) {
        short8 af = *(const short8*)(pA  + k0);
        short8 b0 = *(const short8*)(pB0 + k0);
        short8 b1 = *(const short8*)(pB1 + k0);
        short8 b2 = *(const short8*)(pB2 + k0);
        short8 b3 = *(const short8*)(pB3 + k0);
        acc0 = __builtin_amdgcn_mfma_f32_16x16x32_bf16(af, b0, acc0, 0, 0, 0);
        acc1 = __builtin_amdgcn_mfma_f32_16x16x32_bf16(af, b1, acc1, 0, 0, 0);
        acc2 = __builtin_amdgcn_mfma_f32_16x16x32_bf16(af, b2, acc2, 0, 0, 0);
        acc3 = __builtin_amdgcn_mfma_f32_16x16x32_bf16(af, b3, acc3, 0, 0, 0);
    }

    // C/D layout: col = lane&15, row = quad*4 + reg
    const int rbase = tm * 64 + wave * 16 + quad * 4;
#pragma unroll
    for (int r = 0; r < 4; r++) {
        int gr = rbase + r;
        if (gr >= M) continue;
        size_t o = (size_t)gr * N + tn * 64 + l16;
        C[o]      = f2bf(acc0[r]);
        C[o + 16] = f2bf(acc1[r]);
        C[o + 32] = f2bf(acc2[r]);
        C[o + 48] = f2bf(acc3[r]);
    }
}

// ---------------- gather aggregation, F=512, bf16 in/out (single plane) ----------------

#define GMAX 1024

__global__ __launch_bounds__(256) void gather512_kernel(
    const unsigned short* __restrict__ hb,
    unsigned short* __restrict__ out_h,
    const int* __restrict__ csr_src, const int* __restrict__ row_start,
    const float* __restrict__ dinv, const float* __restrict__ bias, int n)
{
    __shared__ int   s_idx[GMAX];
    __shared__ float s_w[GMAX];
    __shared__ float s_part[512];

    const int node = blockIdx.x;
    const int tid = threadIdx.x;
    const int half = tid >> 7;
    const int slot = tid & 127;
    const float di = dinv[node];

    const int beg = row_start[node], end = row_start[node + 1];

    float4 acc = make_float4(0.f, 0.f, 0.f, 0.f);

    for (int c0 = beg; c0 < end; c0 += GMAX) {
        int cnt = min(end - c0, GMAX);
        for (int p = tid; p < cnt; p += 256) {
            int s = csr_src[c0 + p];
            s_idx[p] = s;
            s_w[p] = dinv[s] * di;
        }
        __syncthreads();
        for (int p = half; p < cnt; p += 2) {
            int s = s_idx[p];
            float w = s_w[p];
            ushort4 r = *(const ushort4*)&hb[(size_t)s * 512 + slot * 4];
            acc.x += w * bf2f(r.x);
            acc.y += w * bf2f(r.y);
            acc.z += w * bf2f(r.z);
            acc.w += w * bf2f(r.w);
        }
        __syncthreads();
    }

    if (half == 1) *(float4*)&s_part[slot * 4] = acc;
    __syncthreads();
    if (half == 0) {
        float4 o = *(const float4*)&s_part[slot * 4];
        ushort4 rs = *(const ushort4*)&hb[(size_t)node * 512 + slot * 4];
        float4 b4 = *(const float4*)&bias[slot * 4];
        float dd = di * di;
        float vx = fmaxf(acc.x + o.x + dd * bf2f(rs.x) + b4.x, 0.f);
        float vy = fmaxf(acc.y + o.y + dd * bf2f(rs.y) + b4.y, 0.f);
        float vz = fmaxf(acc.z + o.z + dd * bf2f(rs.z) + b4.z, 0.f);
        float vw = fmaxf(acc.w + o.w + dd * bf2f(rs.w) + b4.w, 0.f);
        ushort4 ho;
        ho.x = f2bf(vx); ho.y = f2bf(vy); ho.z = f2bf(vz); ho.w = f2bf(vw);
        *(ushort4*)&out_h[(size_t)node * 512 + slot * 4] = ho;
    }
}

// ---------------- small GEMM: h3[M,10] = A[M,512] @ Wc, A bf16 ----------------

__global__ __launch_bounds__(256) void gemm_small_kernel(
    const unsigned short* __restrict__ Ahp,
    const float* __restrict__ W, float* __restrict__ C, int M, int K)
{
    __shared__ float Ws[512 * 10];
    for (int i = threadIdx.x; i < K * 10; i += blockDim.x) Ws[i] = W[i];
    __syncthreads();

    const int wave = threadIdx.x >> 6;
    const int lane = threadIdx.x & 63;
    const int row = blockIdx.x * (blockDim.x >> 6) + wave;
    if (row >= M) return;

    float acc[10];
#pragma unroll
    for (int c = 0; c < 10; c++) acc[c] = 0.f;

    for (int k = lane; k < K; k += 64) {
        float a = bf2f(Ahp[(size_t)row * K + k]);
#pragma unroll
        for (int c = 0; c < 10; c++) acc[c] += a * Ws[k * 10 + c];
    }
#pragma unroll
    for (int c = 0; c < 10; c++) {
#pragma unroll
        for (int off = 32; off; off >>= 1) acc[c] += __shfl_down(acc[c], off);
    }
    if (lane == 0) {
#pragma unroll
        for (int c = 0; c < 10; c++) C[(size_t)row * 10 + c] = acc[c];
    }
}

// ---------------- fused gather(F=10) + log_softmax ----------------

__global__ __launch_bounds__(256) void gather10_softmax_kernel(
    const float* __restrict__ h3, float* __restrict__ out,
    const int* __restrict__ csr_src, const int* __restrict__ row_start,
    const float* __restrict__ dinv, const float* __restrict__ bc, int n)
{
    const int wv = threadIdx.x >> 6;
    const int lane = threadIdx.x & 63;
    const int g = lane / 10;
    const int c = lane - g * 10;
    const int node = blockIdx.x * 24 + wv * 6 + g;
    const bool active = (lane < 60) && (node < n);

    float acc = 0.f;
    if (active) {
        float di = dinv[node];
        acc = h3[(size_t)node * 10 + c] * di * di + bc[c];
        int beg = row_start[node], end = row_start[node + 1];
        for (int p = beg; p < end; ++p) {
            int s = csr_src[p];
            acc += h3[(size_t)s * 10 + c] * dinv[s] * di;
        }
    }
    const int base = g * 10;
    float vj[10];
#pragma unroll
    for (int j = 0; j < 10; j++) vj[j] = __shfl(acc, base + j);
    if (active) {
        float m = vj[0];
#pragma unroll
        for (int j = 1; j < 10; j++) m = fmaxf(m, vj[j]);
        float ssum = 0.f;
#pragma unroll
        for (int j = 0; j < 10; j++) ssum += __expf(vj[j] - m);
        out[(size_t)node * 10 + c] = acc - (m + __logf(ssum));
    }
}

// ---------------- launch ----------------

extern "C" void kernel_launch(void* const* d_in, const int* in_sizes, int n_in,
                              void* d_out, int out_size, void* d_ws, size_t ws_size,
                              hipStream_t stream)
{
    const float* x   = (const float*)d_in[0];
    const int*   ei  = (const int*)d_in[1];
    const float* W1  = (const float*)d_in[2];
    const float* b1  = (const float*)d_in[3];
    const float* W2  = (const float*)d_in[4];
    const float* b2  = (const float*)d_in[5];
    const float* Wc  = (const float*)d_in[6];
    const float* bc  = (const float*)d_in[7];
    float* out = (float*)d_out;

    const int IN_FEATS = 784;
    const int KP1 = 800;
    const int H = 512;
    const int NC = 10;
    const int n = in_sizes[0] / IN_FEATS;   // 10000
    const int E = in_sizes[1] / 2;          // 160000
    const int* src = ei;
    const int* dst = ei + E;

    // workspace layout (~40 MB)
    char* ws = (char*)d_ws;
    unsigned short* Hb   = (unsigned short*)ws; ws += (size_t)n * H * sizeof(unsigned short);
    unsigned short* Xh   = (unsigned short*)ws; ws += (size_t)n * KP1 * sizeof(unsigned short);
    unsigned short* AhB  = (unsigned short*)ws; ws += (size_t)n * H * sizeof(unsigned short);
    unsigned short* W1hT = (unsigned short*)ws; ws += (size_t)KP1 * H * sizeof(unsigned short);
    unsigned short* W2hT = (unsigned short*)ws; ws += (size_t)H * H * sizeof(unsigned short);
    float* dinv      = (float*)ws;             ws += (size_t)n * sizeof(float);
    int*   deg       = (int*)ws;               ws += (size_t)n * sizeof(int);
    int*   cursor    = (int*)ws;               ws += (size_t)n * sizeof(int);
    int*   csr_src   = (int*)ws;               ws += (size_t)E * sizeof(int);
    int*   row_start = (int*)ws;               ws += (size_t)(n + 1) * sizeof(int);
    float* h3        = (float*)ws;             ws += (size_t)n * NC * sizeof(float);

    hipMemsetAsync(deg, 0, (size_t)n * sizeof(int), stream);

    // ---- fused prep ----
    const int bX  = ((size_t)n * KP1 + 255) / 256;
    const int bW1 = (H * KP1 + 255) / 256;
    const int bW2 = (H * H + 255) / 256;
    const int bE  = (E + 255) / 256;
    prep_kernel<<<bX + bW1 + bW2 + bE, 256, 0, stream>>>(
        x, Xh, W1, W1hT, W2, W2hT, dst, deg,
        n, IN_FEATS, KP1, H, E, bX, bW1, bW2);

    scan_kernel<<<1, 1024, 0, stream>>>(deg, row_start, cursor, dinv, n);
    fill_csr_kernel<<<(E + 255) / 256, 256, 0, stream>>>(src, dst, cursor, csr_src, E);

    const int tiles_m = (n + 63) / 64;                      // 157
    const int gemm_grid = ((tiles_m + 7) / 8) * 64;         // 1280 (24 early-exit)

    // ---- layer 1 ----
    gemm_bf16_kernel<<<gemm_grid, 256, 0, stream>>>(Xh, W1hT, Hb, n, H, KP1, tiles_m);
    gather512_kernel<<<n, 256, 0, stream>>>(Hb, AhB, csr_src, row_start, dinv, b1, n);

    // ---- layer 2 ----
    gemm_bf16_kernel<<<gemm_grid, 256, 0, stream>>>(AhB, W2hT, Hb, n, H, H, tiles_m);
    gather512_kernel<<<n, 256, 0, stream>>>(Hb, AhB, csr_src, row_start, dinv, b2, n);

    // ---- layer 3 + softmax ----
    gemm_small_kernel<<<(n + 3) / 4, 256, 0, stream>>>(AhB, Wc, h3, n, H);
    gather10_softmax_kernel<<<(n + 23) / 24, 256, 0, stream>>>(h3, out, csr_src, row_start, dinv, bc, n);
}

// Round 11
// 254.893 us; speedup vs baseline: 1.2115x; 1.2115x over previous
//
#include <hip/hip_runtime.h>
#include <hip/hip_bf16.h>
#include <math.h>

typedef __attribute__((ext_vector_type(8))) short short8;
typedef __attribute__((ext_vector_type(4))) float f32x4;

__device__ inline unsigned short f2bf(float f) {
    unsigned int u = __float_as_uint(f);
    unsigned int r = u + 0x7fffu + ((u >> 16) & 1u);   // RTNE
    return (unsigned short)(r >> 16);
}
__device__ inline float bf2f(unsigned short h) {
    return __uint_as_float(((unsigned int)h) << 16);
}

// async global->LDS, 16 B per lane; LDS dest = wave-uniform base + lane*16
__device__ __forceinline__ void gld16(const unsigned short* g, unsigned short* l) {
    __builtin_amdgcn_global_load_lds(
        (const __attribute__((address_space(1))) unsigned int*)g,
        (__attribute__((address_space(3))) unsigned int*)l, 16, 0, 0);
}

// ---------------- fused prep: convX (bf16) + convW1 (bf16,T) + convW2 (bf16,T) + degree count ----------------

__global__ void prep_kernel(const float* __restrict__ x,
                            unsigned short* __restrict__ Xh,
                            const float* __restrict__ W1, unsigned short* __restrict__ W1hT,
                            const float* __restrict__ W2, unsigned short* __restrict__ W2hT,
                            const int* __restrict__ dst, int* __restrict__ deg,
                            int M, int K1, int Kp1, int H, int E,
                            int bX, int bW1, int bW2)
{
    const int b = blockIdx.x;
    const int tid = threadIdx.x;
    if (b < bX) {
        int id = b * 256 + tid;
        if (id < M * Kp1) {
            int r = id / Kp1;
            int k = id - r * Kp1;
            float v = (k < K1) ? x[(size_t)r * K1 + k] : 0.f;
            Xh[id] = f2bf(v);
        }
    } else if (b < bX + bW1) {
        int id = (b - bX) * 256 + tid;
        if (id < H * Kp1) {
            int nrow = id / Kp1;
            int k = id - nrow * Kp1;
            float v = (k < K1) ? W1[(size_t)k * H + nrow] : 0.f;
            W1hT[id] = f2bf(v);
        }
    } else if (b < bX + bW1 + bW2) {
        int id = (b - bX - bW1) * 256 + tid;
        if (id < H * H) {
            int nrow = id / H;
            int k = id - nrow * H;
            W2hT[id] = f2bf(W2[(size_t)k * H + nrow]);
        }
    } else {
        int e = (b - bX - bW1 - bW2) * 256 + tid;
        if (e < E) atomicAdd(&deg[dst[e]], 1);
    }
}

// ---------------- one-block scan (1024 threads) -> row_start + cursor; also dinv ----------------

__global__ __launch_bounds__(1024) void scan_kernel(const int* __restrict__ deg,
                                                    int* __restrict__ row_start,
                                                    int* __restrict__ cursor,
                                                    float* __restrict__ dinv, int n)
{
    __shared__ int swave[16];
    __shared__ int s_run;
    const int lane = threadIdx.x & 63;
    const int w = threadIdx.x >> 6;
    if (threadIdx.x == 0) s_run = 0;
    __syncthreads();

    for (int base = 0; base < n; base += 1024) {
        int i = base + threadIdx.x;
        int v = (i < n) ? deg[i] : 0;
        int incl = v;
#pragma unroll
        for (int off = 1; off < 64; off <<= 1) {
            int t = __shfl_up(incl, off);
            if (lane >= off) incl += t;
        }
        if (lane == 63) swave[w] = incl;
        __syncthreads();
        int wpre = 0, total = 0;
#pragma unroll
        for (int j = 0; j < 16; j++) {
            int sv = swave[j];
            if (j < w) wpre += sv;
            total += sv;
        }
        int run = s_run;
        if (i < n) {
            int rs = run + wpre + incl - v;
            row_start[i] = rs;
            cursor[i] = rs;
            dinv[i] = rsqrtf((float)v + 1.0f);
        }
        __syncthreads();
        if (threadIdx.x == 0) s_run = run + total;
        __syncthreads();
    }
    if (threadIdx.x == 0) row_start[n] = s_run;
}

// ---------------- CSR fill (absolute cursor) ----------------

__global__ void fill_csr_kernel(const int* __restrict__ src, const int* __restrict__ dst,
                                int* __restrict__ cursor, int* __restrict__ csr_src, int E)
{
    int e = blockIdx.x * blockDim.x + threadIdx.x;
    if (e >= E) return;
    int d = dst[e];
    int pos = atomicAdd(&cursor[d], 1);
    csr_src[pos] = src[e];
}

// ---------------- MFMA GEMM: Hb[M,N](bf16) = A @ B, single bf16 term ----------------
// Tile 128x64, BK=32, 256 threads (4 waves, 2x2 wave grid).
// Staging via global_load_lds width=16 (async, no VGPR round-trip), unpadded 64 B LDS rows.
// Per wave per K-step: 3 x 1KB async stages + 6 ds_read_b128 + 8 MFMAs.
// XCD swizzle: blocks with equal j%8 share the A row-tile on one XCD's L2.

#define TBK 32

__global__ __launch_bounds__(256) void gemm_mfma_kernel(
    const unsigned short* __restrict__ AhG,
    const unsigned short* __restrict__ WhT,
    unsigned short* __restrict__ Hb, int M, int N, int Kp, int tiles_m)
{
    const int j = blockIdx.x;
    const int tn = (j >> 3) & 7;
    const int tm = (j >> 6) * 8 + (j & 7);
    if (tm >= tiles_m) return;

    __shared__ unsigned short Ah[128 * TBK];   // rows of 64 B, contiguous
    __shared__ unsigned short Bh[64 * TBK];

    const int tid  = threadIdx.x;
    const int wave = tid >> 6;
    const int lane = tid & 63;
    const int quad = lane >> 4;
    const int l16  = lane & 15;
    const int row0 = tm * 128;
    const int col0 = tn * 64;
    const int rh = (wave & 1) * 64;      // wave row-half (64 rows)
    const int ch = (wave >> 1) * 32;     // wave col-half (32 cols)

    // staging: lane i -> row i>>2, k-chunk (i&3)*8, LDS byte 16*i from wave base
    const int srow = lane >> 2;          // 0..15
    const int skc  = (lane & 3) * 8;     // 0,8,16,24
    int ga0 = row0 + wave * 32 + srow;        if (ga0 >= M) ga0 = M - 1;
    int ga1 = row0 + wave * 32 + 16 + srow;   if (ga1 >= M) ga1 = M - 1;
    const unsigned short* gA0 = AhG + (size_t)ga0 * Kp + skc;
    const unsigned short* gA1 = AhG + (size_t)ga1 * Kp + skc;
    const unsigned short* gB  = WhT + (size_t)(col0 + wave * 16 + srow) * Kp + skc;
    unsigned short* lA0 = &Ah[(wave * 32) * TBK];        // wave-uniform bases
    unsigned short* lA1 = &Ah[(wave * 32 + 16) * TBK];
    unsigned short* lB  = &Bh[(wave * 16) * TBK];

    f32x4 acc[4][2];
#pragma unroll
    for (int b = 0; b < 4; b++)
#pragma unroll
        for (int c = 0; c < 2; c++) acc[b][c] = (f32x4){0.f, 0.f, 0.f, 0.f};

    for (int k0 = 0; k0 < Kp; k0 += TBK) {
        gld16(gA0 + k0, lA0);
        gld16(gA1 + k0, lA1);
        gld16(gB  + k0, lB);
        __syncthreads();

        short8 ah[4];
#pragma unroll
        for (int b = 0; b < 4; b++)
            ah[b] = *(const short8*)&Ah[(rh + b * 16 + l16) * TBK + quad * 8];
#pragma unroll
        for (int ct = 0; ct < 2; ct++) {
            short8 bh = *(const short8*)&Bh[(ch + ct * 16 + l16) * TBK + quad * 8];
#pragma unroll
            for (int b = 0; b < 4; b++)
                acc[b][ct] = __builtin_amdgcn_mfma_f32_16x16x32_bf16(ah[b], bh, acc[b][ct], 0, 0, 0);
        }
        __syncthreads();
    }

    // epilogue: C/D layout col=lane&15, row=quad*4+reg; bf16 store
#pragma unroll
    for (int b = 0; b < 4; b++) {
#pragma unroll
        for (int ct = 0; ct < 2; ct++) {
            int gc = col0 + ch + ct * 16 + l16;
#pragma unroll
            for (int r = 0; r < 4; r++) {
                int gr = row0 + rh + b * 16 + quad * 4 + r;
                if (gr < M) Hb[(size_t)gr * N + gc] = f2bf(acc[b][ct][r]);
            }
        }
    }
}

// ---------------- gather aggregation, F=512, bf16 in/out (single plane) ----------------

#define GMAX 1024

__global__ __launch_bounds__(256) void gather512_kernel(
    const unsigned short* __restrict__ hb,
    unsigned short* __restrict__ out_h,
    const int* __restrict__ csr_src, const int* __restrict__ row_start,
    const float* __restrict__ dinv, const float* __restrict__ bias, int n)
{
    __shared__ int   s_idx[GMAX];
    __shared__ float s_w[GMAX];
    __shared__ float s_part[512];

    const int node = blockIdx.x;
    const int tid = threadIdx.x;
    const int half = tid >> 7;
    const int slot = tid & 127;
    const float di = dinv[node];

    const int beg = row_start[node], end = row_start[node + 1];

    float4 acc = make_float4(0.f, 0.f, 0.f, 0.f);

    for (int c0 = beg; c0 < end; c0 += GMAX) {
        int cnt = min(end - c0, GMAX);
        for (int p = tid; p < cnt; p += 256) {
            int s = csr_src[c0 + p];
            s_idx[p] = s;
            s_w[p] = dinv[s] * di;
        }
        __syncthreads();
        for (int p = half; p < cnt; p += 2) {
            int s = s_idx[p];
            float w = s_w[p];
            ushort4 r = *(const ushort4*)&hb[(size_t)s * 512 + slot * 4];
            acc.x += w * bf2f(r.x);
            acc.y += w * bf2f(r.y);
            acc.z += w * bf2f(r.z);
            acc.w += w * bf2f(r.w);
        }
        __syncthreads();
    }

    if (half == 1) *(float4*)&s_part[slot * 4] = acc;
    __syncthreads();
    if (half == 0) {
        float4 o = *(const float4*)&s_part[slot * 4];
        ushort4 rs = *(const ushort4*)&hb[(size_t)node * 512 + slot * 4];
        float4 b4 = *(const float4*)&bias[slot * 4];
        float dd = di * di;
        float vx = fmaxf(acc.x + o.x + dd * bf2f(rs.x) + b4.x, 0.f);
        float vy = fmaxf(acc.y + o.y + dd * bf2f(rs.y) + b4.y, 0.f);
        float vz = fmaxf(acc.z + o.z + dd * bf2f(rs.z) + b4.z, 0.f);
        float vw = fmaxf(acc.w + o.w + dd * bf2f(rs.w) + b4.w, 0.f);
        ushort4 ho;
        ho.x = f2bf(vx); ho.y = f2bf(vy); ho.z = f2bf(vz); ho.w = f2bf(vw);
        *(ushort4*)&out_h[(size_t)node * 512 + slot * 4] = ho;
    }
}

// ---------------- small GEMM: h3[M,10] = A[M,512] @ Wc, A bf16 ----------------

__global__ __launch_bounds__(256) void gemm_small_kernel(
    const unsigned short* __restrict__ Ahp,
    const float* __restrict__ W, float* __restrict__ C, int M, int K)
{
    __shared__ float Ws[512 * 10];
    for (int i = threadIdx.x; i < K * 10; i += blockDim.x) Ws[i] = W[i];
    __syncthreads();

    const int wave = threadIdx.x >> 6;
    const int lane = threadIdx.x & 63;
    const int row = blockIdx.x * (blockDim.x >> 6) + wave;
    if (row >= M) return;

    float acc[10];
#pragma unroll
    for (int c = 0; c < 10; c++) acc[c] = 0.f;

    for (int k = lane; k < K; k += 64) {
        float a = bf2f(Ahp[(size_t)row * K + k]);
#pragma unroll
        for (int c = 0; c < 10; c++) acc[c] += a * Ws[k * 10 + c];
    }
#pragma unroll
    for (int c = 0; c < 10; c++) {
#pragma unroll
        for (int off = 32; off; off >>= 1) acc[c] += __shfl_down(acc[c], off);
    }
    if (lane == 0) {
#pragma unroll
        for (int c = 0; c < 10; c++) C[(size_t)row * 10 + c] = acc[c];
    }
}

// ---------------- fused gather(F=10) + log_softmax ----------------

__global__ __launch_bounds__(256) void gather10_softmax_kernel(
    const float* __restrict__ h3, float* __restrict__ out,
    const int* __restrict__ csr_src, const int* __restrict__ row_start,
    const float* __restrict__ dinv, const float* __restrict__ bc, int n)
{
    const int wv = threadIdx.x >> 6;
    const int lane = threadIdx.x & 63;
    const int g = lane / 10;
    const int c = lane - g * 10;
    const int node = blockIdx.x * 24 + wv * 6 + g;
    const bool active = (lane < 60) && (node < n);

    float acc = 0.f;
    if (active) {
        float di = dinv[node];
        acc = h3[(size_t)node * 10 + c] * di * di + bc[c];
        int beg = row_start[node], end = row_start[node + 1];
        for (int p = beg; p < end; ++p) {
            int s = csr_src[p];
            acc += h3[(size_t)s * 10 + c] * dinv[s] * di;
        }
    }
    const int base = g * 10;
    float vj[10];
#pragma unroll
    for (int j = 0; j < 10; j++) vj[j] = __shfl(acc, base + j);
    if (active) {
        float m = vj[0];
#pragma unroll
        for (int j = 1; j < 10; j++) m = fmaxf(m, vj[j]);
        float ssum = 0.f;
#pragma unroll
        for (int j = 0; j < 10; j++) ssum += __expf(vj[j] - m);
        out[(size_t)node * 10 + c] = acc - (m + __logf(ssum));
    }
}

// ---------------- launch ----------------

extern "C" void kernel_launch(void* const* d_in, const int* in_sizes, int n_in,
                              void* d_out, int out_size, void* d_ws, size_t ws_size,
                              hipStream_t stream)
{
    const float* x   = (const float*)d_in[0];
    const int*   ei  = (const int*)d_in[1];
    const float* W1  = (const float*)d_in[2];
    const float* b1  = (const float*)d_in[3];
    const float* W2  = (const float*)d_in[4];
    const float* b2  = (const float*)d_in[5];
    const float* Wc  = (const float*)d_in[6];
    const float* bc  = (const float*)d_in[7];
    float* out = (float*)d_out;

    const int IN_FEATS = 784;
    const int KP1 = 800;
    const int H = 512;
    const int NC = 10;
    const int n = in_sizes[0] / IN_FEATS;   // 10000
    const int E = in_sizes[1] / 2;          // 160000
    const int* src = ei;
    const int* dst = ei + E;

    // workspace layout (~40 MB)
    char* ws = (char*)d_ws;
    unsigned short* Hb   = (unsigned short*)ws; ws += (size_t)n * H * sizeof(unsigned short);
    unsigned short* Xh   = (unsigned short*)ws; ws += (size_t)n * KP1 * sizeof(unsigned short);
    unsigned short* AhB  = (unsigned short*)ws; ws += (size_t)n * H * sizeof(unsigned short);
    unsigned short* W1hT = (unsigned short*)ws; ws += (size_t)KP1 * H * sizeof(unsigned short);
    unsigned short* W2hT = (unsigned short*)ws; ws += (size_t)H * H * sizeof(unsigned short);
    float* dinv      = (float*)ws;             ws += (size_t)n * sizeof(float);
    int*   deg       = (int*)ws;               ws += (size_t)n * sizeof(int);
    int*   cursor    = (int*)ws;               ws += (size_t)n * sizeof(int);
    int*   csr_src   = (int*)ws;               ws += (size_t)E * sizeof(int);
    int*   row_start = (int*)ws;               ws += (size_t)(n + 1) * sizeof(int);
    float* h3        = (float*)ws;             ws += (size_t)n * NC * sizeof(float);

    hipMemsetAsync(deg, 0, (size_t)n * sizeof(int), stream);

    // ---- fused prep ----
    const int bX  = ((size_t)n * KP1 + 255) / 256;
    const int bW1 = (H * KP1 + 255) / 256;
    const int bW2 = (H * H + 255) / 256;
    const int bE  = (E + 255) / 256;
    prep_kernel<<<bX + bW1 + bW2 + bE, 256, 0, stream>>>(
        x, Xh, W1, W1hT, W2, W2hT, dst, deg,
        n, IN_FEATS, KP1, H, E, bX, bW1, bW2);

    scan_kernel<<<1, 1024, 0, stream>>>(deg, row_start, cursor, dinv, n);
    fill_csr_kernel<<<(E + 255) / 256, 256, 0, stream>>>(src, dst, cursor, csr_src, E);

    const int tiles_m = (n + 127) / 128;                    // 79
    const int gemm_grid = ((tiles_m + 7) / 8) * 64;         // 640 (8 early-exit)

    // ---- layer 1 ----
    gemm_mfma_kernel<<<gemm_grid, 256, 0, stream>>>(Xh, W1hT, Hb, n, H, KP1, tiles_m);
    gather512_kernel<<<n, 256, 0, stream>>>(Hb, AhB, csr_src, row_start, dinv, b1, n);

    // ---- layer 2 ----
    gemm_mfma_kernel<<<gemm_grid, 256, 0, stream>>>(AhB, W2hT, Hb, n, H, H, tiles_m);
    gather512_kernel<<<n, 256, 0, stream>>>(Hb, AhB, csr_src, row_start, dinv, b2, n);

    // ---- layer 3 + softmax ----
    gemm_small_kernel<<<(n + 3) / 4, 256, 0, stream>>>(AhB, Wc, h3, n, H);
    gather10_softmax_kernel<<<(n + 23) / 24, 256, 0, stream>>>(h3, out, csr_src, row_start, dinv, bc, n);
}

// Round 12
// 246.135 us; speedup vs baseline: 1.2546x; 1.0356x over previous
//
#include <hip/hip_runtime.h>
#include <hip/hip_bf16.h>
#include <math.h>

typedef __attribute__((ext_vector_type(8))) short short8;
typedef __attribute__((ext_vector_type(8))) unsigned short us8;
typedef __attribute__((ext_vector_type(4))) float f32x4;

__device__ inline unsigned short f2bf(float f) {
    unsigned int u = __float_as_uint(f);
    unsigned int r = u + 0x7fffu + ((u >> 16) & 1u);   // RTNE
    return (unsigned short)(r >> 16);
}
__device__ inline float bf2f(unsigned short h) {
    return __uint_as_float(((unsigned int)h) << 16);
}

// async global->LDS, 16 B per lane; LDS dest = wave-uniform base + lane*16
__device__ __forceinline__ void gld16(const unsigned short* g, unsigned short* l) {
    __builtin_amdgcn_global_load_lds(
        (const __attribute__((address_space(1))) unsigned int*)g,
        (__attribute__((address_space(3))) unsigned int*)l, 16, 0, 0);
}

// ---------------- fused prep: convX (bf16) + convW1 (bf16,T) + convW2 (bf16,T) + degree count ----------------

__global__ void prep_kernel(const float* __restrict__ x,
                            unsigned short* __restrict__ Xh,
                            const float* __restrict__ W1, unsigned short* __restrict__ W1hT,
                            const float* __restrict__ W2, unsigned short* __restrict__ W2hT,
                            const int* __restrict__ dst, int* __restrict__ deg,
                            int M, int K1, int Kp1, int H, int E,
                            int bX, int bW1, int bW2)
{
    const int b = blockIdx.x;
    const int tid = threadIdx.x;
    if (b < bX) {
        int id = b * 256 + tid;
        if (id < M * Kp1) {
            int r = id / Kp1;
            int k = id - r * Kp1;
            float v = (k < K1) ? x[(size_t)r * K1 + k] : 0.f;
            Xh[id] = f2bf(v);
        }
    } else if (b < bX + bW1) {
        int id = (b - bX) * 256 + tid;
        if (id < H * Kp1) {
            int nrow = id / Kp1;
            int k = id - nrow * Kp1;
            float v = (k < K1) ? W1[(size_t)k * H + nrow] : 0.f;
            W1hT[id] = f2bf(v);
        }
    } else if (b < bX + bW1 + bW2) {
        int id = (b - bX - bW1) * 256 + tid;
        if (id < H * H) {
            int nrow = id / H;
            int k = id - nrow * H;
            W2hT[id] = f2bf(W2[(size_t)k * H + nrow]);
        }
    } else {
        int e = (b - bX - bW1 - bW2) * 256 + tid;
        if (e < E) atomicAdd(&deg[dst[e]], 1);
    }
}

// ---------------- one-block scan (1024 threads) -> row_start + cursor; also dinv ----------------

__global__ __launch_bounds__(1024) void scan_kernel(const int* __restrict__ deg,
                                                    int* __restrict__ row_start,
                                                    int* __restrict__ cursor,
                                                    float* __restrict__ dinv, int n)
{
    __shared__ int swave[16];
    __shared__ int s_run;
    const int lane = threadIdx.x & 63;
    const int w = threadIdx.x >> 6;
    if (threadIdx.x == 0) s_run = 0;
    __syncthreads();

    for (int base = 0; base < n; base += 1024) {
        int i = base + threadIdx.x;
        int v = (i < n) ? deg[i] : 0;
        int incl = v;
#pragma unroll
        for (int off = 1; off < 64; off <<= 1) {
            int t = __shfl_up(incl, off);
            if (lane >= off) incl += t;
        }
        if (lane == 63) swave[w] = incl;
        __syncthreads();
        int wpre = 0, total = 0;
#pragma unroll
        for (int j = 0; j < 16; j++) {
            int sv = swave[j];
            if (j < w) wpre += sv;
            total += sv;
        }
        int run = s_run;
        if (i < n) {
            int rs = run + wpre + incl - v;
            row_start[i] = rs;
            cursor[i] = rs;
            dinv[i] = rsqrtf((float)v + 1.0f);
        }
        __syncthreads();
        if (threadIdx.x == 0) s_run = run + total;
        __syncthreads();
    }
    if (threadIdx.x == 0) row_start[n] = s_run;
}

// ---------------- CSR fill (absolute cursor) ----------------

__global__ void fill_csr_kernel(const int* __restrict__ src, const int* __restrict__ dst,
                                int* __restrict__ cursor, int* __restrict__ csr_src, int E)
{
    int e = blockIdx.x * blockDim.x + threadIdx.x;
    if (e >= E) return;
    int d = dst[e];
    int pos = atomicAdd(&cursor[d], 1);
    csr_src[pos] = src[e];
}

// ---------------- MFMA GEMM: Hb[M,N](bf16) = A @ B, single bf16 term ----------------
// Tile 128x64, BK=32, 256 threads (4 waves, 2x2 wave grid).
// Staging via global_load_lds width=16 (async), unpadded 64 B LDS rows.
// XCD swizzle: blocks with equal j%8 share the A row-tile on one XCD's L2.

#define TBK 32

__global__ __launch_bounds__(256) void gemm_mfma_kernel(
    const unsigned short* __restrict__ AhG,
    const unsigned short* __restrict__ WhT,
    unsigned short* __restrict__ Hb, int M, int N, int Kp, int tiles_m)
{
    const int j = blockIdx.x;
    const int tn = (j >> 3) & 7;
    const int tm = (j >> 6) * 8 + (j & 7);
    if (tm >= tiles_m) return;

    __shared__ unsigned short Ah[128 * TBK];
    __shared__ unsigned short Bh[64 * TBK];

    const int tid  = threadIdx.x;
    const int wave = tid >> 6;
    const int lane = tid & 63;
    const int quad = lane >> 4;
    const int l16  = lane & 15;
    const int row0 = tm * 128;
    const int col0 = tn * 64;
    const int rh = (wave & 1) * 64;
    const int ch = (wave >> 1) * 32;

    const int srow = lane >> 2;
    const int skc  = (lane & 3) * 8;
    int ga0 = row0 + wave * 32 + srow;        if (ga0 >= M) ga0 = M - 1;
    int ga1 = row0 + wave * 32 + 16 + srow;   if (ga1 >= M) ga1 = M - 1;
    const unsigned short* gA0 = AhG + (size_t)ga0 * Kp + skc;
    const unsigned short* gA1 = AhG + (size_t)ga1 * Kp + skc;
    const unsigned short* gB  = WhT + (size_t)(col0 + wave * 16 + srow) * Kp + skc;
    unsigned short* lA0 = &Ah[(wave * 32) * TBK];
    unsigned short* lA1 = &Ah[(wave * 32 + 16) * TBK];
    unsigned short* lB  = &Bh[(wave * 16) * TBK];

    f32x4 acc[4][2];
#pragma unroll
    for (int b = 0; b < 4; b++)
#pragma unroll
        for (int c = 0; c < 2; c++) acc[b][c] = (f32x4){0.f, 0.f, 0.f, 0.f};

    for (int k0 = 0; k0 < Kp; k0 += TBK) {
        gld16(gA0 + k0, lA0);
        gld16(gA1 + k0, lA1);
        gld16(gB  + k0, lB);
        __syncthreads();

        short8 ah[4];
#pragma unroll
        for (int b = 0; b < 4; b++)
            ah[b] = *(const short8*)&Ah[(rh + b * 16 + l16) * TBK + quad * 8];
#pragma unroll
        for (int ct = 0; ct < 2; ct++) {
            short8 bh = *(const short8*)&Bh[(ch + ct * 16 + l16) * TBK + quad * 8];
#pragma unroll
            for (int b = 0; b < 4; b++)
                acc[b][ct] = __builtin_amdgcn_mfma_f32_16x16x32_bf16(ah[b], bh, acc[b][ct], 0, 0, 0);
        }
        __syncthreads();
    }

#pragma unroll
    for (int b = 0; b < 4; b++) {
#pragma unroll
        for (int ct = 0; ct < 2; ct++) {
            int gc = col0 + ch + ct * 16 + l16;
#pragma unroll
            for (int r = 0; r < 4; r++) {
                int gr = row0 + rh + b * 16 + quad * 4 + r;
                if (gr < M) Hb[(size_t)gr * N + gc] = f2bf(acc[b][ct][r]);
            }
        }
    }
}

// ---------------- gather aggregation, F=512: WAVE per node, no LDS/barriers ----------------
// Lane l holds feats l*8..l*8+7 (16 B). Neighbor id/weight via wave-uniform loads; unroll-2
// keeps two 1 KB row reads in flight. out = bf16(relu(agg + self*di^2 + bias)).

__global__ __launch_bounds__(256) void gather512_kernel(
    const unsigned short* __restrict__ hb,
    unsigned short* __restrict__ out_h,
    const int* __restrict__ csr_src, const int* __restrict__ row_start,
    const float* __restrict__ dinv, const float* __restrict__ bias, int n)
{
    const int wv = threadIdx.x >> 6;
    const int lane = threadIdx.x & 63;
    const int node = blockIdx.x * 4 + wv;
    if (node >= n) return;
    const float di = dinv[node];
    const int fo = lane * 8;

    us8 self = *(const us8*)&hb[(size_t)node * 512 + fo];
    float4 b0 = *(const float4*)&bias[fo];
    float4 b1 = *(const float4*)&bias[fo + 4];
    const float dd = di * di;
    float acc[8];
    acc[0] = dd * bf2f(self[0]) + b0.x;
    acc[1] = dd * bf2f(self[1]) + b0.y;
    acc[2] = dd * bf2f(self[2]) + b0.z;
    acc[3] = dd * bf2f(self[3]) + b0.w;
    acc[4] = dd * bf2f(self[4]) + b1.x;
    acc[5] = dd * bf2f(self[5]) + b1.y;
    acc[6] = dd * bf2f(self[6]) + b1.z;
    acc[7] = dd * bf2f(self[7]) + b1.w;

    int p = row_start[node];
    const int end = row_start[node + 1];
    for (; p + 1 < end; p += 2) {
        int s0 = csr_src[p], s1 = csr_src[p + 1];
        float w0 = dinv[s0] * di, w1 = dinv[s1] * di;
        us8 r0 = *(const us8*)&hb[(size_t)s0 * 512 + fo];
        us8 r1 = *(const us8*)&hb[(size_t)s1 * 512 + fo];
#pragma unroll
        for (int i = 0; i < 8; i++) acc[i] += w0 * bf2f(r0[i]) + w1 * bf2f(r1[i]);
    }
    if (p < end) {
        int s = csr_src[p];
        float w = dinv[s] * di;
        us8 r = *(const us8*)&hb[(size_t)s * 512 + fo];
#pragma unroll
        for (int i = 0; i < 8; i++) acc[i] += w * bf2f(r[i]);
    }

    us8 o;
#pragma unroll
    for (int i = 0; i < 8; i++) o[i] = f2bf(fmaxf(acc[i], 0.f));
    *(us8*)&out_h[(size_t)node * 512 + fo] = o;
}

// ---------------- small GEMM: h3[M,10] = A[M,512] @ Wc ----------------
// 1024 threads = 16 waves = 16 rows/block (625 blocks -> 4x less Wc staging).
// Wc transposed in LDS [c][k] so lanes do conflict-free ds_read_b128; full K in registers.

__global__ __launch_bounds__(1024) void gemm_small_kernel(
    const unsigned short* __restrict__ Ahp,
    const float* __restrict__ W, float* __restrict__ C, int M, int K)
{
    __shared__ float WsT[10 * 512];   // 20 KB, [c][k]
    for (int i = threadIdx.x; i < 10 * 512; i += 1024) {
        int c = i >> 9, k = i & 511;
        WsT[i] = W[k * 10 + c];
    }
    __syncthreads();

    const int wave = threadIdx.x >> 6;
    const int lane = threadIdx.x & 63;
    const int row = blockIdx.x * 16 + wave;
    if (row >= M) return;

    // lane covers k = lane*4..+3 and +256
    ushort4 a0 = *(const ushort4*)&Ahp[(size_t)row * K + lane * 4];
    ushort4 a1 = *(const ushort4*)&Ahp[(size_t)row * K + lane * 4 + 256];
    float a[8];
    a[0] = bf2f(a0.x); a[1] = bf2f(a0.y); a[2] = bf2f(a0.z); a[3] = bf2f(a0.w);
    a[4] = bf2f(a1.x); a[5] = bf2f(a1.y); a[6] = bf2f(a1.z); a[7] = bf2f(a1.w);

    float acc[10];
#pragma unroll
    for (int c = 0; c < 10; c++) {
        float4 w0 = *(const float4*)&WsT[c * 512 + lane * 4];
        float4 w1 = *(const float4*)&WsT[c * 512 + lane * 4 + 256];
        acc[c] = a[0] * w0.x + a[1] * w0.y + a[2] * w0.z + a[3] * w0.w
               + a[4] * w1.x + a[5] * w1.y + a[6] * w1.z + a[7] * w1.w;
    }
#pragma unroll
    for (int c = 0; c < 10; c++) {
#pragma unroll
        for (int off = 32; off; off >>= 1) acc[c] += __shfl_down(acc[c], off);
    }
    if (lane == 0) {
#pragma unroll
        for (int c = 0; c < 10; c++) C[(size_t)row * 10 + c] = acc[c];
    }
}

// ---------------- fused gather(F=10) + log_softmax ----------------

__global__ __launch_bounds__(256) void gather10_softmax_kernel(
    const float* __restrict__ h3, float* __restrict__ out,
    const int* __restrict__ csr_src, const int* __restrict__ row_start,
    const float* __restrict__ dinv, const float* __restrict__ bc, int n)
{
    const int wv = threadIdx.x >> 6;
    const int lane = threadIdx.x & 63;
    const int g = lane / 10;
    const int c = lane - g * 10;
    const int node = blockIdx.x * 24 + wv * 6 + g;
    const bool active = (lane < 60) && (node < n);

    float acc = 0.f;
    if (active) {
        float di = dinv[node];
        acc = h3[(size_t)node * 10 + c] * di * di + bc[c];
        int beg = row_start[node], end = row_start[node + 1];
        for (int p = beg; p < end; ++p) {
            int s = csr_src[p];
            acc += h3[(size_t)s * 10 + c] * dinv[s] * di;
        }
    }
    const int base = g * 10;
    float vj[10];
#pragma unroll
    for (int j = 0; j < 10; j++) vj[j] = __shfl(acc, base + j);
    if (active) {
        float m = vj[0];
#pragma unroll
        for (int j = 1; j < 10; j++) m = fmaxf(m, vj[j]);
        float ssum = 0.f;
#pragma unroll
        for (int j = 0; j < 10; j++) ssum += __expf(vj[j] - m);
        out[(size_t)node * 10 + c] = acc - (m + __logf(ssum));
    }
}

// ---------------- launch ----------------

extern "C" void kernel_launch(void* const* d_in, const int* in_sizes, int n_in,
                              void* d_out, int out_size, void* d_ws, size_t ws_size,
                              hipStream_t stream)
{
    const float* x   = (const float*)d_in[0];
    const int*   ei  = (const int*)d_in[1];
    const float* W1  = (const float*)d_in[2];
    const float* b1  = (const float*)d_in[3];
    const float* W2  = (const float*)d_in[4];
    const float* b2  = (const float*)d_in[5];
    const float* Wc  = (const float*)d_in[6];
    const float* bc  = (const float*)d_in[7];
    float* out = (float*)d_out;

    const int IN_FEATS = 784;
    const int KP1 = 800;
    const int H = 512;
    const int NC = 10;
    const int n = in_sizes[0] / IN_FEATS;   // 10000
    const int E = in_sizes[1] / 2;          // 160000
    const int* src = ei;
    const int* dst = ei + E;

    // workspace layout (~40 MB)
    char* ws = (char*)d_ws;
    unsigned short* Hb   = (unsigned short*)ws; ws += (size_t)n * H * sizeof(unsigned short);
    unsigned short* Xh   = (unsigned short*)ws; ws += (size_t)n * KP1 * sizeof(unsigned short);
    unsigned short* AhB  = (unsigned short*)ws; ws += (size_t)n * H * sizeof(unsigned short);
    unsigned short* W1hT = (unsigned short*)ws; ws += (size_t)KP1 * H * sizeof(unsigned short);
    unsigned short* W2hT = (unsigned short*)ws; ws += (size_t)H * H * sizeof(unsigned short);
    float* dinv      = (float*)ws;             ws += (size_t)n * sizeof(float);
    int*   deg       = (int*)ws;               ws += (size_t)n * sizeof(int);
    int*   cursor    = (int*)ws;               ws += (size_t)n * sizeof(int);
    int*   csr_src   = (int*)ws;               ws += (size_t)E * sizeof(int);
    int*   row_start = (int*)ws;               ws += (size_t)(n + 1) * sizeof(int);
    float* h3        = (float*)ws;             ws += (size_t)n * NC * sizeof(float);

    hipMemsetAsync(deg, 0, (size_t)n * sizeof(int), stream);

    // ---- fused prep ----
    const int bX  = ((size_t)n * KP1 + 255) / 256;
    const int bW1 = (H * KP1 + 255) / 256;
    const int bW2 = (H * H + 255) / 256;
    const int bE  = (E + 255) / 256;
    prep_kernel<<<bX + bW1 + bW2 + bE, 256, 0, stream>>>(
        x, Xh, W1, W1hT, W2, W2hT, dst, deg,
        n, IN_FEATS, KP1, H, E, bX, bW1, bW2);

    scan_kernel<<<1, 1024, 0, stream>>>(deg, row_start, cursor, dinv, n);
    fill_csr_kernel<<<(E + 255) / 256, 256, 0, stream>>>(src, dst, cursor, csr_src, E);

    const int tiles_m = (n + 127) / 128;                    // 79
    const int gemm_grid = ((tiles_m + 7) / 8) * 64;         // 640 (8 early-exit)

    // ---- layer 1 ----
    gemm_mfma_kernel<<<gemm_grid, 256, 0, stream>>>(Xh, W1hT, Hb, n, H, KP1, tiles_m);
    gather512_kernel<<<(n + 3) / 4, 256, 0, stream>>>(Hb, AhB, csr_src, row_start, dinv, b1, n);

    // ---- layer 2 ----
    gemm_mfma_kernel<<<gemm_grid, 256, 0, stream>>>(AhB, W2hT, Hb, n, H, H, tiles_m);
    gather512_kernel<<<(n + 3) / 4, 256, 0, stream>>>(Hb, AhB, csr_src, row_start, dinv, b2, n);

    // ---- layer 3 + softmax ----
    gemm_small_kernel<<<(n + 15) / 16, 1024, 0, stream>>>(AhB, Wc, h3, n, H);
    gather10_softmax_kernel<<<(n + 23) / 24, 256, 0, stream>>>(h3, out, csr_src, row_start, dinv, bc, n);
}

// Round 13
// 230.941 us; speedup vs baseline: 1.3371x; 1.0658x over previous
//
#include <hip/hip_runtime.h>
#include <hip/hip_bf16.h>
#include <math.h>

typedef __attribute__((ext_vector_type(8))) short short8;
typedef __attribute__((ext_vector_type(8))) unsigned short us8;
typedef __attribute__((ext_vector_type(4))) float f32x4;

__device__ inline unsigned short f2bf(float f) {
    unsigned int u = __float_as_uint(f);
    unsigned int r = u + 0x7fffu + ((u >> 16) & 1u);   // RTNE
    return (unsigned short)(r >> 16);
}
__device__ inline float bf2f(unsigned short h) {
    return __uint_as_float(((unsigned int)h) << 16);
}

// async global->LDS, 16 B per lane; LDS dest = wave-uniform base + lane*16
__device__ __forceinline__ void gld16(const unsigned short* g, unsigned short* l) {
    __builtin_amdgcn_global_load_lds(
        (const __attribute__((address_space(1))) unsigned int*)g,
        (__attribute__((address_space(3))) unsigned int*)l, 16, 0, 0);
}

// ---------------- fused prep: convX + coalesced LDS-tiled W1/W2 transpose-convert + degree count ----
// W transpose: 64x64 tiles; load coalesced (consec. tid -> consec. n), store coalesced
// (consec. tid -> consec. k) via +1-padded LDS.

__global__ __launch_bounds__(256) void prep_kernel(
    const float* __restrict__ x, unsigned short* __restrict__ Xh,
    const float* __restrict__ W1, unsigned short* __restrict__ W1hT,
    const float* __restrict__ W2, unsigned short* __restrict__ W2hT,
    const int* __restrict__ dst, int* __restrict__ deg,
    int M, int K1, int Kp1, int H, int E,
    int bX, int bT1, int bT2)
{
    __shared__ unsigned short T[64][65];
    const int b = blockIdx.x;
    const int tid = threadIdx.x;
    if (b < bX) {
        int id = b * 256 + tid;
        if (id < M * Kp1) {
            int r = id / Kp1;
            int k = id - r * Kp1;
            float v = (k < K1) ? x[(size_t)r * K1 + k] : 0.f;
            Xh[id] = f2bf(v);
        }
    } else if (b < bX + bT1) {
        // W1 [784,512] -> W1hT [512,800]
        int t = b - bX;
        int kt = t >> 3;              // 13 k-tiles
        int nt = t & 7;               // 8 n-tiles
        int k0 = kt * 64, n0 = nt * 64;
        int nl = tid & 63, kl0 = tid >> 6;
#pragma unroll
        for (int j = 0; j < 16; j++) {
            int k = k0 + kl0 + j * 4;
            float v = (k < K1) ? W1[(size_t)k * H + n0 + nl] : 0.f;
            T[kl0 + j * 4][nl] = f2bf(v);
        }
        __syncthreads();
        int kl = tid & 63, nl0 = tid >> 6;
#pragma unroll
        for (int j = 0; j < 16; j++) {
            int k = k0 + kl;
            if (k < Kp1) W1hT[(size_t)(n0 + nl0 + j * 4) * Kp1 + k] = T[kl][nl0 + j * 4];
        }
    } else if (b < bX + bT1 + bT2) {
        // W2 [512,512] -> W2hT [512,512]
        int t = b - bX - bT1;
        int kt = t >> 3, nt = t & 7;
        int k0 = kt * 64, n0 = nt * 64;
        int nl = tid & 63, kl0 = tid >> 6;
#pragma unroll
        for (int j = 0; j < 16; j++) {
            int k = k0 + kl0 + j * 4;
            T[kl0 + j * 4][nl] = f2bf(W2[(size_t)k * H + n0 + nl]);
        }
        __syncthreads();
        int kl = tid & 63, nl0 = tid >> 6;
#pragma unroll
        for (int j = 0; j < 16; j++)
            W2hT[(size_t)(n0 + nl0 + j * 4) * H + k0 + kl] = T[kl][nl0 + j * 4];
    } else {
        int e = (b - bX - bT1 - bT2) * 256 + tid;
        if (e < E) atomicAdd(&deg[dst[e]], 1);
    }
}

// ---------------- one-block scan (1024 threads) -> row_start + cursor; also dinv ----------------

__global__ __launch_bounds__(1024) void scan_kernel(const int* __restrict__ deg,
                                                    int* __restrict__ row_start,
                                                    int* __restrict__ cursor,
                                                    float* __restrict__ dinv, int n)
{
    __shared__ int swave[16];
    __shared__ int s_run;
    const int lane = threadIdx.x & 63;
    const int w = threadIdx.x >> 6;
    if (threadIdx.x == 0) s_run = 0;
    __syncthreads();

    for (int base = 0; base < n; base += 1024) {
        int i = base + threadIdx.x;
        int v = (i < n) ? deg[i] : 0;
        int incl = v;
#pragma unroll
        for (int off = 1; off < 64; off <<= 1) {
            int t = __shfl_up(incl, off);
            if (lane >= off) incl += t;
        }
        if (lane == 63) swave[w] = incl;
        __syncthreads();
        int wpre = 0, total = 0;
#pragma unroll
        for (int j = 0; j < 16; j++) {
            int sv = swave[j];
            if (j < w) wpre += sv;
            total += sv;
        }
        int run = s_run;
        if (i < n) {
            int rs = run + wpre + incl - v;
            row_start[i] = rs;
            cursor[i] = rs;
            dinv[i] = rsqrtf((float)v + 1.0f);
        }
        __syncthreads();
        if (threadIdx.x == 0) s_run = run + total;
        __syncthreads();
    }
    if (threadIdx.x == 0) row_start[n] = s_run;
}

// ---------------- MFMA GEMM (+ optional fused CSR-fill blocks) ----------------
// Blocks [0, gemmBlocks): Hb[M,N](bf16) = A @ B. Tile 128x64, BK=32, 4 waves,
// global_load_lds width-16 staging, XCD swizzle (equal j%8 shares A row-tile).
// Blocks [gemmBlocks, gemmBlocks+fillBlocks): csr_src[cursor[dst]++] = src  (independent work,
// rides this dispatch to hide its latency-bound atomics under GEMM compute).

#define TBK 32

__global__ __launch_bounds__(256) void gemm_mfma_kernel(
    const unsigned short* __restrict__ AhG,
    const unsigned short* __restrict__ WhT,
    unsigned short* __restrict__ Hb, int M, int N, int Kp, int tiles_m,
    int gemmBlocks,
    const int* __restrict__ src, const int* __restrict__ dst,
    int* __restrict__ cursor, int* __restrict__ csr_src, int E)
{
    const int blk = blockIdx.x;
    if (blk >= gemmBlocks) {
        int e = (blk - gemmBlocks) * 256 + threadIdx.x;
        if (e < E) {
            int d = dst[e];
            int pos = atomicAdd(&cursor[d], 1);
            csr_src[pos] = src[e];
        }
        return;
    }

    const int j = blk;
    const int tn = (j >> 3) & 7;
    const int tm = (j >> 6) * 8 + (j & 7);
    if (tm >= tiles_m) return;

    __shared__ unsigned short Ah[128 * TBK];
    __shared__ unsigned short Bh[64 * TBK];

    const int tid  = threadIdx.x;
    const int wave = tid >> 6;
    const int lane = tid & 63;
    const int quad = lane >> 4;
    const int l16  = lane & 15;
    const int row0 = tm * 128;
    const int col0 = tn * 64;
    const int rh = (wave & 1) * 64;
    const int ch = (wave >> 1) * 32;

    const int srow = lane >> 2;
    const int skc  = (lane & 3) * 8;
    int ga0 = row0 + wave * 32 + srow;        if (ga0 >= M) ga0 = M - 1;
    int ga1 = row0 + wave * 32 + 16 + srow;   if (ga1 >= M) ga1 = M - 1;
    const unsigned short* gA0 = AhG + (size_t)ga0 * Kp + skc;
    const unsigned short* gA1 = AhG + (size_t)ga1 * Kp + skc;
    const unsigned short* gB  = WhT + (size_t)(col0 + wave * 16 + srow) * Kp + skc;
    unsigned short* lA0 = &Ah[(wave * 32) * TBK];
    unsigned short* lA1 = &Ah[(wave * 32 + 16) * TBK];
    unsigned short* lB  = &Bh[(wave * 16) * TBK];

    f32x4 acc[4][2];
#pragma unroll
    for (int b = 0; b < 4; b++)
#pragma unroll
        for (int c = 0; c < 2; c++) acc[b][c] = (f32x4){0.f, 0.f, 0.f, 0.f};

    for (int k0 = 0; k0 < Kp; k0 += TBK) {
        gld16(gA0 + k0, lA0);
        gld16(gA1 + k0, lA1);
        gld16(gB  + k0, lB);
        __syncthreads();

        short8 ah[4];
#pragma unroll
        for (int b = 0; b < 4; b++)
            ah[b] = *(const short8*)&Ah[(rh + b * 16 + l16) * TBK + quad * 8];
#pragma unroll
        for (int ct = 0; ct < 2; ct++) {
            short8 bh = *(const short8*)&Bh[(ch + ct * 16 + l16) * TBK + quad * 8];
#pragma unroll
            for (int b = 0; b < 4; b++)
                acc[b][ct] = __builtin_amdgcn_mfma_f32_16x16x32_bf16(ah[b], bh, acc[b][ct], 0, 0, 0);
        }
        __syncthreads();
    }

#pragma unroll
    for (int b = 0; b < 4; b++) {
#pragma unroll
        for (int ct = 0; ct < 2; ct++) {
            int gc = col0 + ch + ct * 16 + l16;
#pragma unroll
            for (int r = 0; r < 4; r++) {
                int gr = row0 + rh + b * 16 + quad * 4 + r;
                if (gr < M) Hb[(size_t)gr * N + gc] = f2bf(acc[b][ct][r]);
            }
        }
    }
}

// ---------------- gather aggregation, F=512: wave per node, unroll-4, no LDS/barriers ----------------

__global__ __launch_bounds__(256) void gather512_kernel(
    const unsigned short* __restrict__ hb,
    unsigned short* __restrict__ out_h,
    const int* __restrict__ csr_src, const int* __restrict__ row_start,
    const float* __restrict__ dinv, const float* __restrict__ bias, int n)
{
    const int wv = threadIdx.x >> 6;
    const int lane = threadIdx.x & 63;
    const int node = blockIdx.x * 4 + wv;
    if (node >= n) return;
    const float di = dinv[node];
    const int fo = lane * 8;

    us8 self = *(const us8*)&hb[(size_t)node * 512 + fo];
    float4 b0 = *(const float4*)&bias[fo];
    float4 b1 = *(const float4*)&bias[fo + 4];
    const float dd = di * di;
    float acc[8];
    acc[0] = dd * bf2f(self[0]) + b0.x;
    acc[1] = dd * bf2f(self[1]) + b0.y;
    acc[2] = dd * bf2f(self[2]) + b0.z;
    acc[3] = dd * bf2f(self[3]) + b0.w;
    acc[4] = dd * bf2f(self[4]) + b1.x;
    acc[5] = dd * bf2f(self[5]) + b1.y;
    acc[6] = dd * bf2f(self[6]) + b1.z;
    acc[7] = dd * bf2f(self[7]) + b1.w;

    int p = row_start[node];
    const int end = row_start[node + 1];
    for (; p + 3 < end; p += 4) {
        int s0 = csr_src[p], s1 = csr_src[p + 1], s2 = csr_src[p + 2], s3 = csr_src[p + 3];
        float w0 = dinv[s0] * di, w1 = dinv[s1] * di, w2 = dinv[s2] * di, w3 = dinv[s3] * di;
        us8 r0 = *(const us8*)&hb[(size_t)s0 * 512 + fo];
        us8 r1 = *(const us8*)&hb[(size_t)s1 * 512 + fo];
        us8 r2 = *(const us8*)&hb[(size_t)s2 * 512 + fo];
        us8 r3 = *(const us8*)&hb[(size_t)s3 * 512 + fo];
#pragma unroll
        for (int i = 0; i < 8; i++)
            acc[i] += w0 * bf2f(r0[i]) + w1 * bf2f(r1[i]) + w2 * bf2f(r2[i]) + w3 * bf2f(r3[i]);
    }
    for (; p < end; ++p) {
        int s = csr_src[p];
        float w = dinv[s] * di;
        us8 r = *(const us8*)&hb[(size_t)s * 512 + fo];
#pragma unroll
        for (int i = 0; i < 8; i++) acc[i] += w * bf2f(r[i]);
    }

    us8 o;
#pragma unroll
    for (int i = 0; i < 8; i++) o[i] = f2bf(fmaxf(acc[i], 0.f));
    *(us8*)&out_h[(size_t)node * 512 + fo] = o;
}

// ---------------- small GEMM: h3[M,10] = A[M,512] @ Wc ----------------

__global__ __launch_bounds__(1024) void gemm_small_kernel(
    const unsigned short* __restrict__ Ahp,
    const float* __restrict__ W, float* __restrict__ C, int M, int K)
{
    __shared__ float WsT[10 * 512];   // [c][k]
    for (int i = threadIdx.x; i < 10 * 512; i += 1024) {
        int c = i >> 9, k = i & 511;
        WsT[i] = W[k * 10 + c];
    }
    __syncthreads();

    const int wave = threadIdx.x >> 6;
    const int lane = threadIdx.x & 63;
    const int row = blockIdx.x * 16 + wave;
    if (row >= M) return;

    ushort4 a0 = *(const ushort4*)&Ahp[(size_t)row * K + lane * 4];
    ushort4 a1 = *(const ushort4*)&Ahp[(size_t)row * K + lane * 4 + 256];
    float a[8];
    a[0] = bf2f(a0.x); a[1] = bf2f(a0.y); a[2] = bf2f(a0.z); a[3] = bf2f(a0.w);
    a[4] = bf2f(a1.x); a[5] = bf2f(a1.y); a[6] = bf2f(a1.z); a[7] = bf2f(a1.w);

    float acc[10];
#pragma unroll
    for (int c = 0; c < 10; c++) {
        float4 w0 = *(const float4*)&WsT[c * 512 + lane * 4];
        float4 w1 = *(const float4*)&WsT[c * 512 + lane * 4 + 256];
        acc[c] = a[0] * w0.x + a[1] * w0.y + a[2] * w0.z + a[3] * w0.w
               + a[4] * w1.x + a[5] * w1.y + a[6] * w1.z + a[7] * w1.w;
    }
#pragma unroll
    for (int c = 0; c < 10; c++) {
#pragma unroll
        for (int off = 32; off; off >>= 1) acc[c] += __shfl_down(acc[c], off);
    }
    if (lane == 0) {
#pragma unroll
        for (int c = 0; c < 10; c++) C[(size_t)row * 10 + c] = acc[c];
    }
}

// ---------------- fused gather(F=10) + log_softmax ----------------

__global__ __launch_bounds__(256) void gather10_softmax_kernel(
    const float* __restrict__ h3, float* __restrict__ out,
    const int* __restrict__ csr_src, const int* __restrict__ row_start,
    const float* __restrict__ dinv, const float* __restrict__ bc, int n)
{
    const int wv = threadIdx.x >> 6;
    const int lane = threadIdx.x & 63;
    const int g = lane / 10;
    const int c = lane - g * 10;
    const int node = blockIdx.x * 24 + wv * 6 + g;
    const bool active = (lane < 60) && (node < n);

    float acc = 0.f;
    if (active) {
        float di = dinv[node];
        acc = h3[(size_t)node * 10 + c] * di * di + bc[c];
        int beg = row_start[node], end = row_start[node + 1];
        for (int p = beg; p < end; ++p) {
            int s = csr_src[p];
            acc += h3[(size_t)s * 10 + c] * dinv[s] * di;
        }
    }
    const int base = g * 10;
    float vj[10];
#pragma unroll
    for (int j = 0; j < 10; j++) vj[j] = __shfl(acc, base + j);
    if (active) {
        float m = vj[0];
#pragma unroll
        for (int j = 1; j < 10; j++) m = fmaxf(m, vj[j]);
        float ssum = 0.f;
#pragma unroll
        for (int j = 0; j < 10; j++) ssum += __expf(vj[j] - m);
        out[(size_t)node * 10 + c] = acc - (m + __logf(ssum));
    }
}

// ---------------- launch ----------------

extern "C" void kernel_launch(void* const* d_in, const int* in_sizes, int n_in,
                              void* d_out, int out_size, void* d_ws, size_t ws_size,
                              hipStream_t stream)
{
    const float* x   = (const float*)d_in[0];
    const int*   ei  = (const int*)d_in[1];
    const float* W1  = (const float*)d_in[2];
    const float* b1  = (const float*)d_in[3];
    const float* W2  = (const float*)d_in[4];
    const float* b2  = (const float*)d_in[5];
    const float* Wc  = (const float*)d_in[6];
    const float* bc  = (const float*)d_in[7];
    float* out = (float*)d_out;

    const int IN_FEATS = 784;
    const int KP1 = 800;
    const int H = 512;
    const int NC = 10;
    const int n = in_sizes[0] / IN_FEATS;   // 10000
    const int E = in_sizes[1] / 2;          // 160000
    const int* src = ei;
    const int* dst = ei + E;

    // workspace layout (~40 MB)
    char* ws = (char*)d_ws;
    unsigned short* Hb   = (unsigned short*)ws; ws += (size_t)n * H * sizeof(unsigned short);
    unsigned short* Xh   = (unsigned short*)ws; ws += (size_t)n * KP1 * sizeof(unsigned short);
    unsigned short* AhB  = (unsigned short*)ws; ws += (size_t)n * H * sizeof(unsigned short);
    unsigned short* W1hT = (unsigned short*)ws; ws += (size_t)KP1 * H * sizeof(unsigned short);
    unsigned short* W2hT = (unsigned short*)ws; ws += (size_t)H * H * sizeof(unsigned short);
    float* dinv      = (float*)ws;             ws += (size_t)n * sizeof(float);
    int*   deg       = (int*)ws;               ws += (size_t)n * sizeof(int);
    int*   cursor    = (int*)ws;               ws += (size_t)n * sizeof(int);
    int*   csr_src   = (int*)ws;               ws += (size_t)E * sizeof(int);
    int*   row_start = (int*)ws;               ws += (size_t)(n + 1) * sizeof(int);
    float* h3        = (float*)ws;             ws += (size_t)n * NC * sizeof(float);

    hipMemsetAsync(deg, 0, (size_t)n * sizeof(int), stream);

    // ---- fused prep ----
    const int bX  = ((size_t)n * KP1 + 255) / 256;     // 31250
    const int bT1 = ((KP1 + 63) / 64) * (H / 64);      // 13*8 = 104
    const int bT2 = (H / 64) * (H / 64);               // 64
    const int bE  = (E + 255) / 256;                   // 625
    prep_kernel<<<bX + bT1 + bT2 + bE, 256, 0, stream>>>(
        x, Xh, W1, W1hT, W2, W2hT, dst, deg,
        n, IN_FEATS, KP1, H, E, bX, bT1, bT2);

    scan_kernel<<<1, 1024, 0, stream>>>(deg, row_start, cursor, dinv, n);

    const int tiles_m = (n + 127) / 128;                    // 79
    const int gemmBlocks = ((tiles_m + 7) / 8) * 64;        // 640 (8 early-exit)

    // ---- layer 1 (+ CSR fill riding the dispatch) ----
    gemm_mfma_kernel<<<gemmBlocks + bE, 256, 0, stream>>>(
        Xh, W1hT, Hb, n, H, KP1, tiles_m, gemmBlocks, src, dst, cursor, csr_src, E);
    gather512_kernel<<<(n + 3) / 4, 256, 0, stream>>>(Hb, AhB, csr_src, row_start, dinv, b1, n);

    // ---- layer 2 ----
    gemm_mfma_kernel<<<gemmBlocks, 256, 0, stream>>>(
        AhB, W2hT, Hb, n, H, H, tiles_m, gemmBlocks, src, dst, cursor, csr_src, 0);
    gather512_kernel<<<(n + 3) / 4, 256, 0, stream>>>(Hb, AhB, csr_src, row_start, dinv, b2, n);

    // ---- layer 3 + softmax ----
    gemm_small_kernel<<<(n + 15) / 16, 1024, 0, stream>>>(AhB, Wc, h3, n, H);
    gather10_softmax_kernel<<<(n + 23) / 24, 256, 0, stream>>>(h3, out, csr_src, row_start, dinv, bc, n);
}

// Round 14
// 218.191 us; speedup vs baseline: 1.4153x; 1.0584x over previous
//
#include <hip/hip_runtime.h>
#include <hip/hip_bf16.h>
#include <math.h>

typedef __attribute__((ext_vector_type(8))) short short8;
typedef __attribute__((ext_vector_type(8))) unsigned short us8;
typedef __attribute__((ext_vector_type(4))) float f32x4;

__device__ inline unsigned short f2bf(float f) {
    unsigned int u = __float_as_uint(f);
    unsigned int r = u + 0x7fffu + ((u >> 16) & 1u);   // RTNE
    return (unsigned short)(r >> 16);
}
__device__ inline float bf2f(unsigned short h) {
    return __uint_as_float(((unsigned int)h) << 16);
}

// async global->LDS, 16 B per lane; LDS dest = wave-uniform base + lane*16
__device__ __forceinline__ void gld16(const unsigned short* g, unsigned short* l) {
    __builtin_amdgcn_global_load_lds(
        (const __attribute__((address_space(1))) unsigned int*)g,
        (__attribute__((address_space(3))) unsigned int*)l, 16, 0, 0);
}

// ---------------- fused prep: convX (float4-vectorized) + LDS-tiled W1/W2 transpose + degree count ----

__global__ __launch_bounds__(256) void prep_kernel(
    const float* __restrict__ x, unsigned short* __restrict__ Xh,
    const float* __restrict__ W1, unsigned short* __restrict__ W1hT,
    const float* __restrict__ W2, unsigned short* __restrict__ W2hT,
    const int* __restrict__ dst, int* __restrict__ deg,
    int M, int K1, int Kp1, int H, int E,
    int bX, int bT1, int bT2)
{
    __shared__ unsigned short T[64][65];
    const int b = blockIdx.x;
    const int tid = threadIdx.x;
    if (b < bX) {
        // X convert, 4 elems/thread (K1 % 4 == 0; k >= K1 zero-pad)
        int id = b * 256 + tid;                 // float4 index
        int kp4 = Kp1 >> 2;                     // 200
        int k14 = K1 >> 2;                      // 196
        if (id < M * kp4) {
            int r = id / kp4;
            int k4 = id - r * kp4;
            ushort4 o;
            if (k4 < k14) {
                float4 v = *(const float4*)&x[(size_t)r * K1 + k4 * 4];
                o.x = f2bf(v.x); o.y = f2bf(v.y); o.z = f2bf(v.z); o.w = f2bf(v.w);
            } else {
                o.x = o.y = o.z = o.w = 0;
            }
            *(ushort4*)&Xh[(size_t)r * Kp1 + k4 * 4] = o;
        }
    } else if (b < bX + bT1) {
        // W1 [784,512] -> W1hT [512,800]
        int t = b - bX;
        int kt = t >> 3;              // 13 k-tiles
        int nt = t & 7;               // 8 n-tiles
        int k0 = kt * 64, n0 = nt * 64;
        int nl = tid & 63, kl0 = tid >> 6;
#pragma unroll
        for (int j = 0; j < 16; j++) {
            int k = k0 + kl0 + j * 4;
            float v = (k < K1) ? W1[(size_t)k * H + n0 + nl] : 0.f;
            T[kl0 + j * 4][nl] = f2bf(v);
        }
        __syncthreads();
        int kl = tid & 63, nl0 = tid >> 6;
#pragma unroll
        for (int j = 0; j < 16; j++) {
            int k = k0 + kl;
            if (k < Kp1) W1hT[(size_t)(n0 + nl0 + j * 4) * Kp1 + k] = T[kl][nl0 + j * 4];
        }
    } else if (b < bX + bT1 + bT2) {
        // W2 [512,512] -> W2hT [512,512]
        int t = b - bX - bT1;
        int kt = t >> 3, nt = t & 7;
        int k0 = kt * 64, n0 = nt * 64;
        int nl = tid & 63, kl0 = tid >> 6;
#pragma unroll
        for (int j = 0; j < 16; j++) {
            int k = k0 + kl0 + j * 4;
            T[kl0 + j * 4][nl] = f2bf(W2[(size_t)k * H + n0 + nl]);
        }
        __syncthreads();
        int kl = tid & 63, nl0 = tid >> 6;
#pragma unroll
        for (int j = 0; j < 16; j++)
            W2hT[(size_t)(n0 + nl0 + j * 4) * H + k0 + kl] = T[kl][nl0 + j * 4];
    } else {
        int e = (b - bX - bT1 - bT2) * 256 + tid;
        if (e < E) atomicAdd(&deg[dst[e]], 1);
    }
}

// ---------------- one-block scan (1024 threads, prefetched) -> row_start + cursor; also dinv ----------------

__global__ __launch_bounds__(1024) void scan_kernel(const int* __restrict__ deg,
                                                    int* __restrict__ row_start,
                                                    int* __restrict__ cursor,
                                                    float* __restrict__ dinv, int n)
{
    __shared__ int swave[16];
    __shared__ int s_run;
    const int lane = threadIdx.x & 63;
    const int w = threadIdx.x >> 6;
    if (threadIdx.x == 0) s_run = 0;
    __syncthreads();

    const int nch = (n + 1023) >> 10;      // 10 for n=10000 (max 16 supported)
    int vv[16];
#pragma unroll 4
    for (int j = 0; j < nch; j++) {
        int i = j * 1024 + threadIdx.x;
        vv[j] = (i < n) ? deg[i] : 0;      // all loads issued up front, latency overlapped
    }

    for (int j = 0; j < nch; j++) {
        int i = j * 1024 + threadIdx.x;
        int v = vv[j];
        int incl = v;
#pragma unroll
        for (int off = 1; off < 64; off <<= 1) {
            int t = __shfl_up(incl, off);
            if (lane >= off) incl += t;
        }
        if (lane == 63) swave[w] = incl;
        __syncthreads();
        int wpre = 0, total = 0;
#pragma unroll
        for (int jj = 0; jj < 16; jj++) {
            int sv = swave[jj];
            if (jj < w) wpre += sv;
            total += sv;
        }
        int run = s_run;
        if (i < n) {
            int rs = run + wpre + incl - v;
            row_start[i] = rs;
            cursor[i] = rs;
            dinv[i] = rsqrtf((float)v + 1.0f);
        }
        __syncthreads();
        if (threadIdx.x == 0) s_run = run + total;
        __syncthreads();
    }
    if (threadIdx.x == 0) row_start[n] = s_run;
}

// ---------------- MFMA GEMM (+ optional fused CSR-fill blocks) ----------------

#define TBK 32

__global__ __launch_bounds__(256) void gemm_mfma_kernel(
    const unsigned short* __restrict__ AhG,
    const unsigned short* __restrict__ WhT,
    unsigned short* __restrict__ Hb, int M, int N, int Kp, int tiles_m,
    int gemmBlocks,
    const int* __restrict__ src, const int* __restrict__ dst,
    int* __restrict__ cursor, int* __restrict__ csr_src, int E)
{
    const int blk = blockIdx.x;
    if (blk >= gemmBlocks) {
        int e = (blk - gemmBlocks) * 256 + threadIdx.x;
        if (e < E) {
            int d = dst[e];
            int pos = atomicAdd(&cursor[d], 1);
            csr_src[pos] = src[e];
        }
        return;
    }

    const int j = blk;
    const int tn = (j >> 3) & 7;
    const int tm = (j >> 6) * 8 + (j & 7);
    if (tm >= tiles_m) return;

    __shared__ unsigned short Ah[128 * TBK];
    __shared__ unsigned short Bh[64 * TBK];

    const int tid  = threadIdx.x;
    const int wave = tid >> 6;
    const int lane = tid & 63;
    const int quad = lane >> 4;
    const int l16  = lane & 15;
    const int row0 = tm * 128;
    const int col0 = tn * 64;
    const int rh = (wave & 1) * 64;
    const int ch = (wave >> 1) * 32;

    const int srow = lane >> 2;
    const int skc  = (lane & 3) * 8;
    int ga0 = row0 + wave * 32 + srow;        if (ga0 >= M) ga0 = M - 1;
    int ga1 = row0 + wave * 32 + 16 + srow;   if (ga1 >= M) ga1 = M - 1;
    const unsigned short* gA0 = AhG + (size_t)ga0 * Kp + skc;
    const unsigned short* gA1 = AhG + (size_t)ga1 * Kp + skc;
    const unsigned short* gB  = WhT + (size_t)(col0 + wave * 16 + srow) * Kp + skc;
    unsigned short* lA0 = &Ah[(wave * 32) * TBK];
    unsigned short* lA1 = &Ah[(wave * 32 + 16) * TBK];
    unsigned short* lB  = &Bh[(wave * 16) * TBK];

    f32x4 acc[4][2];
#pragma unroll
    for (int b = 0; b < 4; b++)
#pragma unroll
        for (int c = 0; c < 2; c++) acc[b][c] = (f32x4){0.f, 0.f, 0.f, 0.f};

    for (int k0 = 0; k0 < Kp; k0 += TBK) {
        gld16(gA0 + k0, lA0);
        gld16(gA1 + k0, lA1);
        gld16(gB  + k0, lB);
        __syncthreads();

        short8 ah[4];
#pragma unroll
        for (int b = 0; b < 4; b++)
            ah[b] = *(const short8*)&Ah[(rh + b * 16 + l16) * TBK + quad * 8];
#pragma unroll
        for (int ct = 0; ct < 2; ct++) {
            short8 bh = *(const short8*)&Bh[(ch + ct * 16 + l16) * TBK + quad * 8];
#pragma unroll
            for (int b = 0; b < 4; b++)
                acc[b][ct] = __builtin_amdgcn_mfma_f32_16x16x32_bf16(ah[b], bh, acc[b][ct], 0, 0, 0);
        }
        __syncthreads();
    }

#pragma unroll
    for (int b = 0; b < 4; b++) {
#pragma unroll
        for (int ct = 0; ct < 2; ct++) {
            int gc = col0 + ch + ct * 16 + l16;
#pragma unroll
            for (int r = 0; r < 4; r++) {
                int gr = row0 + rh + b * 16 + quad * 4 + r;
                if (gr < M) Hb[(size_t)gr * N + gc] = f2bf(acc[b][ct][r]);
            }
        }
    }
}

// ---------------- gather aggregation, F=512: wave per node, unroll-4, no LDS/barriers ----------------

__global__ __launch_bounds__(256) void gather512_kernel(
    const unsigned short* __restrict__ hb,
    unsigned short* __restrict__ out_h,
    const int* __restrict__ csr_src, const int* __restrict__ row_start,
    const float* __restrict__ dinv, const float* __restrict__ bias, int n)
{
    const int wv = threadIdx.x >> 6;
    const int lane = threadIdx.x & 63;
    const int node = blockIdx.x * 4 + wv;
    if (node >= n) return;
    const float di = dinv[node];
    const int fo = lane * 8;

    us8 self = *(const us8*)&hb[(size_t)node * 512 + fo];
    float4 b0 = *(const float4*)&bias[fo];
    float4 b1 = *(const float4*)&bias[fo + 4];
    const float dd = di * di;
    float acc[8];
    acc[0] = dd * bf2f(self[0]) + b0.x;
    acc[1] = dd * bf2f(self[1]) + b0.y;
    acc[2] = dd * bf2f(self[2]) + b0.z;
    acc[3] = dd * bf2f(self[3]) + b0.w;
    acc[4] = dd * bf2f(self[4]) + b1.x;
    acc[5] = dd * bf2f(self[5]) + b1.y;
    acc[6] = dd * bf2f(self[6]) + b1.z;
    acc[7] = dd * bf2f(self[7]) + b1.w;

    int p = row_start[node];
    const int end = row_start[node + 1];
    for (; p + 3 < end; p += 4) {
        int s0 = csr_src[p], s1 = csr_src[p + 1], s2 = csr_src[p + 2], s3 = csr_src[p + 3];
        float w0 = dinv[s0] * di, w1 = dinv[s1] * di, w2 = dinv[s2] * di, w3 = dinv[s3] * di;
        us8 r0 = *(const us8*)&hb[(size_t)s0 * 512 + fo];
        us8 r1 = *(const us8*)&hb[(size_t)s1 * 512 + fo];
        us8 r2 = *(const us8*)&hb[(size_t)s2 * 512 + fo];
        us8 r3 = *(const us8*)&hb[(size_t)s3 * 512 + fo];
#pragma unroll
        for (int i = 0; i < 8; i++)
            acc[i] += w0 * bf2f(r0[i]) + w1 * bf2f(r1[i]) + w2 * bf2f(r2[i]) + w3 * bf2f(r3[i]);
    }
    for (; p < end; ++p) {
        int s = csr_src[p];
        float w = dinv[s] * di;
        us8 r = *(const us8*)&hb[(size_t)s * 512 + fo];
#pragma unroll
        for (int i = 0; i < 8; i++) acc[i] += w * bf2f(r[i]);
    }

    us8 o;
#pragma unroll
    for (int i = 0; i < 8; i++) o[i] = f2bf(fmaxf(acc[i], 0.f));
    *(us8*)&out_h[(size_t)node * 512 + fo] = o;
}

// ---------------- small GEMM: h3[M,10] = A[M,512] @ Wc ----------------

__global__ __launch_bounds__(1024) void gemm_small_kernel(
    const unsigned short* __restrict__ Ahp,
    const float* __restrict__ W, float* __restrict__ C, int M, int K)
{
    __shared__ float WsT[10 * 512];   // [c][k]
    for (int i = threadIdx.x; i < 10 * 512; i += 1024) {
        int c = i >> 9, k = i & 511;
        WsT[i] = W[k * 10 + c];
    }
    __syncthreads();

    const int wave = threadIdx.x >> 6;
    const int lane = threadIdx.x & 63;
    const int row = blockIdx.x * 16 + wave;
    if (row >= M) return;

    ushort4 a0 = *(const ushort4*)&Ahp[(size_t)row * K + lane * 4];
    ushort4 a1 = *(const ushort4*)&Ahp[(size_t)row * K + lane * 4 + 256];
    float a[8];
    a[0] = bf2f(a0.x); a[1] = bf2f(a0.y); a[2] = bf2f(a0.z); a[3] = bf2f(a0.w);
    a[4] = bf2f(a1.x); a[5] = bf2f(a1.y); a[6] = bf2f(a1.z); a[7] = bf2f(a1.w);

    float acc[10];
#pragma unroll
    for (int c = 0; c < 10; c++) {
        float4 w0 = *(const float4*)&WsT[c * 512 + lane * 4];
        float4 w1 = *(const float4*)&WsT[c * 512 + lane * 4 + 256];
        acc[c] = a[0] * w0.x + a[1] * w0.y + a[2] * w0.z + a[3] * w0.w
               + a[4] * w1.x + a[5] * w1.y + a[6] * w1.z + a[7] * w1.w;
    }
#pragma unroll
    for (int c = 0; c < 10; c++) {
#pragma unroll
        for (int off = 32; off; off >>= 1) acc[c] += __shfl_down(acc[c], off);
    }
    if (lane == 0) {
#pragma unroll
        for (int c = 0; c < 10; c++) C[(size_t)row * 10 + c] = acc[c];
    }
}

// ---------------- fused gather(F=10) + log_softmax: WAVE per node ----------------
// Lanes = edge-group (0..5) x class (0..9); 6 edges x 10 classes per iteration.
// Cross-group reduce via shuffles; softmax on lanes 0..9; coalesced 40 B stores.

__global__ __launch_bounds__(256) void gather10_softmax_kernel(
    const float* __restrict__ h3, float* __restrict__ out,
    const int* __restrict__ csr_src, const int* __restrict__ row_start,
    const float* __restrict__ dinv, const float* __restrict__ bc, int n)
{
    const int wv = threadIdx.x >> 6;
    const int lane = threadIdx.x & 63;
    const int node = blockIdx.x * 4 + wv;
    if (node >= n) return;

    const int eg = lane / 10;          // 0..5 (lane<60), 6 for lanes 60..63
    const int c  = lane - eg * 10;
    const bool active = lane < 60;
    const float di = dinv[node];
    const int beg = row_start[node], end = row_start[node + 1];

    float acc = 0.f;
    if (active) {
        for (int p = beg + eg; p < end; p += 6) {
            int s = csr_src[p];
            acc += h3[(size_t)s * 10 + c] * dinv[s];
        }
        acc *= di;
    }
    // reduce eg-groups: lanes (c, c+10, ..., c+50) -> lane c
    acc += __shfl(acc, lane + 30);                         // lanes 0..29 pick up eg+3
    float t1 = __shfl(acc, lane + 10);
    float t2 = __shfl(acc, lane + 20);
    if (lane < 10) {
        acc = acc + t1 + t2 + h3[(size_t)node * 10 + c] * di * di + bc[c];
    }
    float vj[10];
#pragma unroll
    for (int j = 0; j < 10; j++) vj[j] = __shfl(acc, j);
    if (lane < 10) {
        float m = vj[0];
#pragma unroll
        for (int j = 1; j < 10; j++) m = fmaxf(m, vj[j]);
        float ssum = 0.f;
#pragma unroll
        for (int j = 0; j < 10; j++) ssum += __expf(vj[j] - m);
        out[(size_t)node * 10 + c] = acc - (m + __logf(ssum));
    }
}

// ---------------- launch ----------------

extern "C" void kernel_launch(void* const* d_in, const int* in_sizes, int n_in,
                              void* d_out, int out_size, void* d_ws, size_t ws_size,
                              hipStream_t stream)
{
    const float* x   = (const float*)d_in[0];
    const int*   ei  = (const int*)d_in[1];
    const float* W1  = (const float*)d_in[2];
    const float* b1  = (const float*)d_in[3];
    const float* W2  = (const float*)d_in[4];
    const float* b2  = (const float*)d_in[5];
    const float* Wc  = (const float*)d_in[6];
    const float* bc  = (const float*)d_in[7];
    float* out = (float*)d_out;

    const int IN_FEATS = 784;
    const int KP1 = 800;
    const int H = 512;
    const int NC = 10;
    const int n = in_sizes[0] / IN_FEATS;   // 10000
    const int E = in_sizes[1] / 2;          // 160000
    const int* src = ei;
    const int* dst = ei + E;

    // workspace layout (~40 MB)
    char* ws = (char*)d_ws;
    unsigned short* Hb   = (unsigned short*)ws; ws += (size_t)n * H * sizeof(unsigned short);
    unsigned short* Xh   = (unsigned short*)ws; ws += (size_t)n * KP1 * sizeof(unsigned short);
    unsigned short* AhB  = (unsigned short*)ws; ws += (size_t)n * H * sizeof(unsigned short);
    unsigned short* W1hT = (unsigned short*)ws; ws += (size_t)KP1 * H * sizeof(unsigned short);
    unsigned short* W2hT = (unsigned short*)ws; ws += (size_t)H * H * sizeof(unsigned short);
    float* dinv      = (float*)ws;             ws += (size_t)n * sizeof(float);
    int*   deg       = (int*)ws;               ws += (size_t)n * sizeof(int);
    int*   cursor    = (int*)ws;               ws += (size_t)n * sizeof(int);
    int*   csr_src   = (int*)ws;               ws += (size_t)E * sizeof(int);
    int*   row_start = (int*)ws;               ws += (size_t)(n + 1) * sizeof(int);
    float* h3        = (float*)ws;             ws += (size_t)n * NC * sizeof(float);

    hipMemsetAsync(deg, 0, (size_t)n * sizeof(int), stream);

    // ---- fused prep ----
    const int bX  = ((size_t)n * (KP1 / 4) + 255) / 256;   // 7813
    const int bT1 = ((KP1 + 63) / 64) * (H / 64);          // 104
    const int bT2 = (H / 64) * (H / 64);                   // 64
    const int bE  = (E + 255) / 256;                       // 625
    prep_kernel<<<bX + bT1 + bT2 + bE, 256, 0, stream>>>(
        x, Xh, W1, W1hT, W2, W2hT, dst, deg,
        n, IN_FEATS, KP1, H, E, bX, bT1, bT2);

    scan_kernel<<<1, 1024, 0, stream>>>(deg, row_start, cursor, dinv, n);

    const int tiles_m = (n + 127) / 128;                    // 79
    const int gemmBlocks = ((tiles_m + 7) / 8) * 64;        // 640 (8 early-exit)

    // ---- layer 1 (+ CSR fill riding the dispatch) ----
    gemm_mfma_kernel<<<gemmBlocks + bE, 256, 0, stream>>>(
        Xh, W1hT, Hb, n, H, KP1, tiles_m, gemmBlocks, src, dst, cursor, csr_src, E);
    gather512_kernel<<<(n + 3) / 4, 256, 0, stream>>>(Hb, AhB, csr_src, row_start, dinv, b1, n);

    // ---- layer 2 ----
    gemm_mfma_kernel<<<gemmBlocks, 256, 0, stream>>>(
        AhB, W2hT, Hb, n, H, H, tiles_m, gemmBlocks, src, dst, cursor, csr_src, 0);
    gather512_kernel<<<(n + 3) / 4, 256, 0, stream>>>(Hb, AhB, csr_src, row_start, dinv, b2, n);

    // ---- layer 3 + softmax ----
    gemm_small_kernel<<<(n + 15) / 16, 1024, 0, stream>>>(AhB, Wc, h3, n, H);
    gather10_softmax_kernel<<<(n + 3) / 4, 256, 0, stream>>>(h3, out, csr_src, row_start, dinv, bc, n);
}